// Round 3
// baseline (171.547 us; speedup 1.0000x reference)
//
#include <hip/hip_runtime.h>
#include <hip/hip_bf16.h>

typedef __attribute__((ext_vector_type(8))) short bf16x8;
typedef __attribute__((ext_vector_type(4))) float f32x4;
typedef __attribute__((ext_vector_type(4))) unsigned short us4;

#define B_ 4
#define S_ 2048
#define E_ 1024
#define H_ 1024
#define M_ (B_ * S_)   // 8192 tokens
#define N3_ (3 * H_)   // 3072 fused QKV columns
#define NTRI_ 136      // lower-tri 128-tiles per batch (16*17/2)

__device__ __forceinline__ unsigned short f2bf(float f) {
  union { float f; unsigned u; } v; v.f = f;
  unsigned r = v.u + 0x7fffu + ((v.u >> 16) & 1u);  // RNE
  return (unsigned short)(r >> 16);
}
__device__ __forceinline__ float bf2f(unsigned short u) {
  union { unsigned u; float f; } v; v.u = ((unsigned)u) << 16; return v.f;
}

// ---------------- K0a: x fp32 -> bf16 (vectorized) ----------------
__global__ __launch_bounds__(256) void k_convert_x(const float* __restrict__ x,
                                                   unsigned short* __restrict__ xb) {
  int i = blockIdx.x * 256 + threadIdx.x;
  const float4 v = reinterpret_cast<const float4*>(x)[i];
  us4 o;
  o[0] = f2bf(v.x); o[1] = f2bf(v.y); o[2] = f2bf(v.z); o[3] = f2bf(v.w);
  reinterpret_cast<us4*>(xb)[i] = o;
}

// ------- K0b: W[E][H] fp32 -> Wt[3H][E] bf16 (transposed, LDS tile) -------
__global__ __launch_bounds__(256) void k_transpose_w(const float* __restrict__ Wq,
                                                     const float* __restrict__ Wk,
                                                     const float* __restrict__ Wv,
                                                     unsigned short* __restrict__ Wt) {
  __shared__ float tile[32][33];
  const int mat = blockIdx.z;
  const float* W = (mat == 0) ? Wq : (mat == 1) ? Wk : Wv;
  const int n0 = blockIdx.x * 32, k0 = blockIdx.y * 32;
  const int tx = threadIdx.x, ty = threadIdx.y;
#pragma unroll
  for (int i = 0; i < 32; i += 8)
    tile[ty + i][tx] = W[(size_t)(k0 + ty + i) * H_ + n0 + tx];
  __syncthreads();
#pragma unroll
  for (int i = 0; i < 32; i += 8) {
    int n = n0 + ty + i;
    Wt[(size_t)(mat * H_ + n) * E_ + k0 + tx] = f2bf(tile[tx][ty + i]);
  }
}

// ===== 8-phase 256x256x64 GEMM machinery (T2+T3+T4+T5) =====
// LDS: linear dest, pre-swizzled global source chunk (q in LDS holds global
// chunk q ^ (row&7)); ds_read applies the same XOR.
__device__ __forceinline__ void stage_half_A(
    const unsigned short* gA /* tile base + k0 */, int ld,
    unsigned short* ldsA /* As + dbuf */, int mh, int w, int srow, int schunk) {
#pragma unroll
  for (int l = 0; l < 2; ++l) {
    const int row0 = l * 128 + mh * 64 + w * 8;  // rows {mh*64..+63} u {128+mh*64..}
    __builtin_amdgcn_global_load_lds(
        (const __attribute__((address_space(1))) unsigned int*)(gA + (size_t)(row0 + srow) * ld + schunk * 8),
        (__attribute__((address_space(3))) unsigned int*)(ldsA + row0 * 64),
        16, 0, 0);
  }
}
__device__ __forceinline__ void stage_half_B(
    const unsigned short* gB, int ld,
    unsigned short* ldsB, int nh, int w, int srow, int schunk) {
#pragma unroll
  for (int l = 0; l < 2; ++l) {
    const int fi = (w * 2 + l) * 8;  // rows with bit5==nh across 4 groups
    const int row0 = (fi >> 5) * 64 + nh * 32 + (fi & 31);
    __builtin_amdgcn_global_load_lds(
        (const __attribute__((address_space(1))) unsigned int*)(gB + (size_t)(row0 + srow) * ld + schunk * 8),
        (__attribute__((address_space(3))) unsigned int*)(ldsB + row0 * 64),
        16, 0, 0);
  }
}

// One phase: quadrant (MH,NH) of this wave's 128x64 C block, full BK=64.
// 12 ds_read_b128 -> stage issue -> barrier -> lgkm0 -> 16 MFMA -> tail -> barrier
#define PHASE(MH, NH, STAGE_STMT, TAIL_STMT)                                     \
  {                                                                              \
    bf16x8 af[4][2], bfv[2][2];                                                  \
    _Pragma("unroll") for (int fm = 0; fm < 4; ++fm) {                           \
      const int ra = wr * 128 + (MH) * 64 + fm * 16 + l15;                       \
      const unsigned short* ap = &As[abuf + ra * 64];                            \
      af[fm][0] = *reinterpret_cast<const bf16x8*>(ap + c0 * 8);                 \
      af[fm][1] = *reinterpret_cast<const bf16x8*>(ap + c1 * 8);                 \
    }                                                                            \
    _Pragma("unroll") for (int fn = 0; fn < 2; ++fn) {                           \
      const int rb = wc * 64 + (NH) * 32 + fn * 16 + l15;                        \
      const unsigned short* bp = &Bs[abuf + rb * 64];                            \
      bfv[fn][0] = *reinterpret_cast<const bf16x8*>(bp + c0 * 8);                \
      bfv[fn][1] = *reinterpret_cast<const bf16x8*>(bp + c1 * 8);                \
    }                                                                            \
    STAGE_STMT;                                                                  \
    __builtin_amdgcn_s_barrier();                                                \
    asm volatile("s_waitcnt lgkmcnt(0)" ::: "memory");                           \
    __builtin_amdgcn_sched_barrier(0);                                           \
    __builtin_amdgcn_s_setprio(1);                                               \
    _Pragma("unroll") for (int fm = 0; fm < 4; ++fm)                             \
      _Pragma("unroll") for (int fn = 0; fn < 2; ++fn) {                         \
        acc[(MH) * 4 + fm][(NH) * 2 + fn] =                                      \
            __builtin_amdgcn_mfma_f32_16x16x32_bf16(                             \
                af[fm][0], bfv[fn][0], acc[(MH) * 4 + fm][(NH) * 2 + fn], 0, 0, 0); \
        acc[(MH) * 4 + fm][(NH) * 2 + fn] =                                      \
            __builtin_amdgcn_mfma_f32_16x16x32_bf16(                             \
                af[fm][1], bfv[fn][1], acc[(MH) * 4 + fm][(NH) * 2 + fn], 0, 0, 0); \
      }                                                                          \
    __builtin_amdgcn_s_setprio(0);                                               \
    TAIL_STMT;                                                                   \
    __builtin_amdgcn_s_barrier();                                                \
  }

// ---------------- K1: fused QKV GEMM, 256x256 8-phase ----------------
__global__ __launch_bounds__(512, 2) void k_gemm_qkv8(
    const unsigned short* __restrict__ xb, const unsigned short* __restrict__ Wt,
    const float* __restrict__ bq, const float* __restrict__ bk,
    const float* __restrict__ bv,
    unsigned short* __restrict__ Qb, unsigned short* __restrict__ Kb,
    unsigned short* __restrict__ Vt) {
  __shared__ __align__(16) unsigned short As[2 * 256 * 64];  // 64 KiB
  __shared__ __align__(16) unsigned short Bs[2 * 256 * 64];  // 64 KiB
  int bid = blockIdx.x;                 // 384 = 8*48, bijective XCD swizzle
  bid = (bid & 7) * 48 + (bid >> 3);
  const int tm = bid / 12, tn = bid % 12;
  const int gm = tm * 256, gn = tn * 256;
  const int tid = threadIdx.x, w = tid >> 6, lane = tid & 63;
  const int wr = w >> 2, wc = w & 3;    // 2M x 4N wave grid; wave C = 128x64
  const int l15 = lane & 15, hi = lane >> 4;
  const int srow = lane >> 3, schunk = (lane & 7) ^ srow;
  const int c0 = hi ^ (lane & 7), c1 = c0 ^ 4;
  const unsigned short* gA = xb + (size_t)gm * E_;
  const unsigned short* gB = Wt + (size_t)gn * E_;

  f32x4 acc[8][4];
#pragma unroll
  for (int i = 0; i < 8; ++i)
#pragma unroll
    for (int j = 0; j < 4; ++j) acc[i][j] = (f32x4)0.0f;

  // prologue: K-tile0 (4 halves) + A0,B0 of K-tile1; wait K-tile0, keep 4 in flight
  stage_half_A(gA, E_, As, 0, w, srow, schunk);
  stage_half_A(gA, E_, As, 1, w, srow, schunk);
  stage_half_B(gB, E_, Bs, 0, w, srow, schunk);
  stage_half_B(gB, E_, Bs, 1, w, srow, schunk);
  stage_half_A(gA + 64, E_, As + 16384, 0, w, srow, schunk);
  stage_half_B(gB + 64, E_, Bs + 16384, 0, w, srow, schunk);
  asm volatile("s_waitcnt vmcnt(4)" ::: "memory");
  __builtin_amdgcn_s_barrier();

  for (int k = 0; k < 14; ++k) {
    const int abuf = (k & 1) << 14;
    const int nbuf = abuf ^ (1 << 14);
    PHASE(0, 0, stage_half_A(gA + (k + 1) * 64, E_, As + nbuf, 1, w, srow, schunk), )
    PHASE(0, 1, stage_half_B(gB + (k + 1) * 64, E_, Bs + nbuf, 1, w, srow, schunk), )
    PHASE(1, 0, stage_half_A(gA + (k + 2) * 64, E_, As + abuf, 0, w, srow, schunk), )
    PHASE(1, 1, stage_half_B(gB + (k + 2) * 64, E_, Bs + abuf, 0, w, srow, schunk),
          asm volatile("s_waitcnt vmcnt(4)" ::: "memory"))
  }
  {  // k = 14: stage last halves of K-tile 15, drain fully
    const int abuf = 0;
    PHASE(0, 0, stage_half_A(gA + 15 * 64, E_, As + 16384, 1, w, srow, schunk), )
    PHASE(0, 1, stage_half_B(gB + 15 * 64, E_, Bs + 16384, 1, w, srow, schunk), )
    PHASE(1, 0, , )
    PHASE(1, 1, , asm volatile("s_waitcnt vmcnt(0)" ::: "memory"))
  }
  {  // k = 15: compute only
    const int abuf = 1 << 14;
    PHASE(0, 0, , )
    PHASE(0, 1, , )
    PHASE(1, 0, , )
    PHASE(1, 1, , )
  }

  // epilogue: bias, bf16, scatter Q/K row-major or V transposed
  const int matid = gn >> 10;
  const float* bias = (matid == 0) ? bq : (matid == 1) ? bk : bv;
#pragma unroll
  for (int mf = 0; mf < 8; ++mf) {
#pragma unroll
    for (int nf = 0; nf < 4; ++nf) {
      const int row0 = gm + wr * 128 + mf * 16 + hi * 4;
      const int col = gn + wc * 64 + nf * 16 + l15;
      const int h = col & 1023;
      const float bb = bias[h];
      if (matid < 2) {
        unsigned short* dst = matid ? Kb : Qb;
#pragma unroll
        for (int r = 0; r < 4; ++r)
          dst[(size_t)(row0 + r) * H_ + h] = f2bf(acc[mf][nf][r] + bb);
      } else {
        const int bat = row0 >> 11, s0 = row0 & 2047;
        us4 pk;
#pragma unroll
        for (int r = 0; r < 4; ++r) pk[r] = f2bf(acc[mf][nf][r] + bb);
        *reinterpret_cast<us4*>(&Vt[(size_t)bat * H_ * S_ + (size_t)h * S_ + s0]) = pk;
      }
    }
  }
}

// ------- K2: scores GEMM (m97 128x128), lower-tri tiles only, packed out -------
__global__ __launch_bounds__(256, 2) void k_gemm_scores(
    const unsigned short* __restrict__ Qb, const unsigned short* __restrict__ Kb,
    unsigned short* __restrict__ Pt) {
  __shared__ unsigned short As[128 * 64];
  __shared__ unsigned short Bs[128 * 64];
  int bid = blockIdx.x;                  // 544 = 8*68, bijective XCD swizzle
  bid = (bid & 7) * 68 + (bid >> 3);
  const int batch = bid / NTRI_;
  const int t = bid % NTRI_;
  int tm = 0;
  while ((tm + 1) * (tm + 2) / 2 <= t) ++tm;
  const int tn = t - tm * (tm + 1) / 2;
  const int gm = tm * 128, gn = tn * 128;
  const int tid = threadIdx.x, w = tid >> 6, lane = tid & 63;
  const int wr = w >> 1, wc = w & 1;
  const int srow = lane >> 3;
  const int schunk = (lane & 7) ^ srow;
  const unsigned short* Abase = Qb + (size_t)batch * S_ * H_;
  const unsigned short* Bbase = Kb + (size_t)batch * S_ * H_;

  f32x4 acc[4][4];
#pragma unroll
  for (int i = 0; i < 4; ++i)
#pragma unroll
    for (int j = 0; j < 4; ++j) acc[i][j] = (f32x4)0.0f;

  for (int kt = 0; kt < 16; ++kt) {
    const int k0 = kt * 64;
#pragma unroll
    for (int i = 0; i < 4; ++i) {
      const int row = w * 32 + i * 8 + srow;
      __builtin_amdgcn_global_load_lds(
          (const __attribute__((address_space(1))) unsigned int*)(Abase + (size_t)(gm + row) * H_ + k0 + schunk * 8),
          (__attribute__((address_space(3))) unsigned int*)(As + (w * 32 + i * 8) * 64),
          16, 0, 0);
      __builtin_amdgcn_global_load_lds(
          (const __attribute__((address_space(1))) unsigned int*)(Bbase + (size_t)(gn + row) * H_ + k0 + schunk * 8),
          (__attribute__((address_space(3))) unsigned int*)(Bs + (w * 32 + i * 8) * 64),
          16, 0, 0);
    }
    __syncthreads();
#pragma unroll
    for (int ks = 0; ks < 2; ++ks) {
      bf16x8 af[4], bfrag[4];
#pragma unroll
      for (int mt = 0; mt < 4; ++mt) {
        const int r16 = wr * 64 + mt * 16 + (lane & 15);
        const int ch = (ks * 4 + (lane >> 4)) ^ (r16 & 7);
        af[mt] = *reinterpret_cast<const bf16x8*>(&As[r16 * 64 + ch * 8]);
      }
#pragma unroll
      for (int nt = 0; nt < 4; ++nt) {
        const int c16 = wc * 64 + nt * 16 + (lane & 15);
        const int ch = (ks * 4 + (lane >> 4)) ^ (c16 & 7);
        bfrag[nt] = *reinterpret_cast<const bf16x8*>(&Bs[c16 * 64 + ch * 8]);
      }
#pragma unroll
      for (int mt = 0; mt < 4; ++mt)
#pragma unroll
        for (int nt = 0; nt < 4; ++nt)
          acc[mt][nt] = __builtin_amdgcn_mfma_f32_16x16x32_bf16(
              af[mt], bfrag[nt], acc[mt][nt], 0, 0, 0);
    }
    __syncthreads();
  }

  const size_t tbase = ((size_t)batch * NTRI_ + (tm * (tm + 1)) / 2 + tn) * 16384;
#pragma unroll
  for (int mt = 0; mt < 4; ++mt) {
#pragma unroll
    for (int nt = 0; nt < 4; ++nt) {
      const int row0 = wr * 64 + mt * 16 + (lane >> 4) * 4;
      const int col = wc * 64 + nt * 16 + (lane & 15);
#pragma unroll
      for (int r = 0; r < 4; ++r)
        Pt[tbase + (size_t)(row0 + r) * 128 + col] = f2bf(acc[mt][nt][r] * 0.03125f);
    }
  }
}

// ------- K3: in-place causal row softmax over packed tri tiles -------
__global__ __launch_bounds__(256) void k_softmax(unsigned short* __restrict__ Pt) {
  const int tid = threadIdx.x, lane = tid & 63;
  const int gr = blockIdx.x * 4 + (tid >> 6);
  const int batch = gr >> 11, q = gr & 2047;
  const int tm = q >> 7, r = q & 127;
  const int W = (tm + 1) << 7;
  const size_t rowb = ((size_t)batch * NTRI_ + (tm * (tm + 1)) / 2) * 16384 + (size_t)r * 128;

  float s[32];
  float mx = -1e30f;
#pragma unroll
  for (int it = 0; it < 4; ++it) {
    const int c = it * 512 + lane * 8;
    if (c < W) {
      const int tn = c >> 7;
      const bf16x8 v = *reinterpret_cast<const bf16x8*>(&Pt[rowb + (size_t)tn * 16384 + (c & 127)]);
#pragma unroll
      for (int j = 0; j < 8; ++j) {
        float f = bf2f((unsigned short)v[j]);
        if (c + j > q) f = -1e30f;
        s[it * 8 + j] = f;
        mx = fmaxf(mx, f);
      }
    } else {
#pragma unroll
      for (int j = 0; j < 8; ++j) s[it * 8 + j] = -1e30f;
    }
  }
#pragma unroll
  for (int off = 32; off; off >>= 1) mx = fmaxf(mx, __shfl_xor(mx, off));
  float sum = 0.f;
#pragma unroll
  for (int it = 0; it < 4; ++it)
#pragma unroll
    for (int j = 0; j < 8; ++j) {
      const float p = __expf(s[it * 8 + j] - mx);
      s[it * 8 + j] = p;
      sum += p;
    }
#pragma unroll
  for (int off = 32; off; off >>= 1) sum += __shfl_xor(sum, off);
  const float inv = 1.0f / sum;
#pragma unroll
  for (int it = 0; it < 4; ++it) {
    const int c = it * 512 + lane * 8;
    if (c < W) {
      const int tn = c >> 7;
      bf16x8 o;
#pragma unroll
      for (int j = 0; j < 8; ++j) o[j] = (short)f2bf(s[it * 8 + j] * inv);
      *reinterpret_cast<bf16x8*>(&Pt[rowb + (size_t)tn * 16384 + (c & 127)]) = o;
    }
  }
}

// ------- K4: O = P.V GEMM, variable-K, heavy/light CU pairing -------
__global__ __launch_bounds__(256, 2) void k_gemm_pv(
    const unsigned short* __restrict__ Pt, const unsigned short* __restrict__ Vt,
    float* __restrict__ out) {
  __shared__ unsigned short As[128 * 64];
  __shared__ unsigned short Bs[128 * 64];
  // bijective heavy<->light pairing: CU partners (b, b+256) get ~constant work
  const int b0 = blockIdx.x;
  const int rk = (b0 < 256) ? b0 : 767 - b0;
  const int tm = 15 - (rk >> 5);
  const int batch = (rk >> 3) & 3;
  const int tn = rk & 7;
  const int gm = tm * 128, gn = tn * 128;
  const int tid = threadIdx.x, w = tid >> 6, lane = tid & 63;
  const int wr = w >> 1, wc = w & 1;
  const int srow = lane >> 3;
  const int schunk = (lane & 7) ^ srow;
  const size_t trow = ((size_t)batch * NTRI_ + (tm * (tm + 1)) / 2) * 16384;
  const unsigned short* Bbase = Vt + (size_t)batch * H_ * S_;
  const int nk = (tm + 1) * 2;

  f32x4 acc[4][4];
#pragma unroll
  for (int i = 0; i < 4; ++i)
#pragma unroll
    for (int j = 0; j < 4; ++j) acc[i][j] = (f32x4)0.0f;

  for (int kt = 0; kt < nk; ++kt) {
    const int ktn = kt >> 1, cin = (kt & 1) * 64;
#pragma unroll
    for (int i = 0; i < 4; ++i) {
      const int row = w * 32 + i * 8 + srow;
      __builtin_amdgcn_global_load_lds(
          (const __attribute__((address_space(1))) unsigned int*)(Pt + trow + (size_t)ktn * 16384 + (size_t)row * 128 + cin + schunk * 8),
          (__attribute__((address_space(3))) unsigned int*)(As + (w * 32 + i * 8) * 64),
          16, 0, 0);
      __builtin_amdgcn_global_load_lds(
          (const __attribute__((address_space(1))) unsigned int*)(Bbase + (size_t)(gn + row) * S_ + kt * 64 + schunk * 8),
          (__attribute__((address_space(3))) unsigned int*)(Bs + (w * 32 + i * 8) * 64),
          16, 0, 0);
    }
    __syncthreads();
#pragma unroll
    for (int ks = 0; ks < 2; ++ks) {
      bf16x8 af[4], bfrag[4];
#pragma unroll
      for (int mt = 0; mt < 4; ++mt) {
        const int r16 = wr * 64 + mt * 16 + (lane & 15);
        const int ch = (ks * 4 + (lane >> 4)) ^ (r16 & 7);
        af[mt] = *reinterpret_cast<const bf16x8*>(&As[r16 * 64 + ch * 8]);
      }
#pragma unroll
      for (int nt = 0; nt < 4; ++nt) {
        const int c16 = wc * 64 + nt * 16 + (lane & 15);
        const int ch = (ks * 4 + (lane >> 4)) ^ (c16 & 7);
        bfrag[nt] = *reinterpret_cast<const bf16x8*>(&Bs[c16 * 64 + ch * 8]);
      }
#pragma unroll
      for (int mt = 0; mt < 4; ++mt)
#pragma unroll
        for (int nt = 0; nt < 4; ++nt)
          acc[mt][nt] = __builtin_amdgcn_mfma_f32_16x16x32_bf16(
              af[mt], bfrag[nt], acc[mt][nt], 0, 0, 0);
    }
    __syncthreads();
  }

#pragma unroll
  for (int mt = 0; mt < 4; ++mt) {
#pragma unroll
    for (int nt = 0; nt < 4; ++nt) {
      const int row0 = gm + wr * 64 + mt * 16 + (lane >> 4) * 4;
      const int col = gn + wc * 64 + nt * 16 + (lane & 15);
#pragma unroll
      for (int r = 0; r < 4; ++r)
        out[(size_t)batch * S_ * H_ + (size_t)(row0 + r) * H_ + col] = acc[mt][nt][r];
    }
  }
}

extern "C" void kernel_launch(void* const* d_in, const int* in_sizes, int n_in,
                              void* d_out, int out_size, void* d_ws, size_t ws_size,
                              hipStream_t stream) {
  const float* x  = (const float*)d_in[0];
  const float* Wq = (const float*)d_in[1];
  const float* bq = (const float*)d_in[2];
  const float* Wk = (const float*)d_in[3];
  const float* bk = (const float*)d_in[4];
  const float* Wv = (const float*)d_in[5];
  const float* bv = (const float*)d_in[6];
  float* out = (float*)d_out;

  // ws layout (bf16 elems): Qb | Kb | Vt | X-region
  // X-region holds xb+Wt during QKV, then the packed tri score/P buffer.
  unsigned short* Qb = (unsigned short*)d_ws;
  unsigned short* Kb = Qb + (size_t)M_ * H_;
  unsigned short* Vt = Kb + (size_t)M_ * H_;
  unsigned short* Xr = Vt + (size_t)M_ * H_;
  unsigned short* xb = Xr;
  unsigned short* Wt = Xr + (size_t)M_ * E_;
  unsigned short* Pt = Xr;

  hipLaunchKernelGGL(k_convert_x, dim3(M_ * E_ / 1024), dim3(256), 0, stream, x, xb);
  hipLaunchKernelGGL(k_transpose_w, dim3(32, 32, 3), dim3(32, 8), 0, stream, Wq, Wk, Wv, Wt);
  hipLaunchKernelGGL(k_gemm_qkv8, dim3(384), dim3(512), 0, stream,
                     xb, Wt, bq, bk, bv, Qb, Kb, Vt);
  hipLaunchKernelGGL(k_gemm_scores, dim3(544), dim3(256), 0, stream, Qb, Kb, Pt);
  hipLaunchKernelGGL(k_softmax, dim3(2048), dim3(256), 0, stream, Pt);
  hipLaunchKernelGGL(k_gemm_pv, dim3(512), dim3(256), 0, stream, Pt, Vt, out);
}

// Round 4
// 157.788 us; speedup vs baseline: 1.0872x; 1.0872x over previous
//
#include <hip/hip_runtime.h>
#include <hip/hip_bf16.h>

typedef __attribute__((ext_vector_type(8))) short bf16x8;
typedef __attribute__((ext_vector_type(4))) float f32x4;
typedef __attribute__((ext_vector_type(4))) unsigned short us4;

#define B_ 4
#define S_ 2048
#define E_ 1024
#define H_ 1024
#define M_ (B_ * S_)   // 8192 tokens
#define N3_ (3 * H_)   // 3072 fused QKV columns
#define NTRI_ 136      // lower-tri 128-tiles per batch (16*17/2)

__device__ __forceinline__ unsigned short f2bf(float f) {
  union { float f; unsigned u; } v; v.f = f;
  unsigned r = v.u + 0x7fffu + ((v.u >> 16) & 1u);  // RNE
  return (unsigned short)(r >> 16);
}
__device__ __forceinline__ float bf2f(unsigned short u) {
  union { unsigned u; float f; } v; v.u = ((unsigned)u) << 16; return v.f;
}

// ---------------- K0a: x fp32 -> bf16 (vectorized) ----------------
__global__ __launch_bounds__(256) void k_convert_x(const float* __restrict__ x,
                                                   unsigned short* __restrict__ xb) {
  int i = blockIdx.x * 256 + threadIdx.x;
  const float4 v = reinterpret_cast<const float4*>(x)[i];
  us4 o;
  o[0] = f2bf(v.x); o[1] = f2bf(v.y); o[2] = f2bf(v.z); o[3] = f2bf(v.w);
  reinterpret_cast<us4*>(xb)[i] = o;
}

// ------- K0b: W[E][H] fp32 -> Wt[3H][E] bf16 (transposed, LDS tile) -------
__global__ __launch_bounds__(256) void k_transpose_w(const float* __restrict__ Wq,
                                                     const float* __restrict__ Wk,
                                                     const float* __restrict__ Wv,
                                                     unsigned short* __restrict__ Wt) {
  __shared__ float tile[32][33];
  const int mat = blockIdx.z;
  const float* W = (mat == 0) ? Wq : (mat == 1) ? Wk : Wv;
  const int n0 = blockIdx.x * 32, k0 = blockIdx.y * 32;
  const int tx = threadIdx.x, ty = threadIdx.y;
#pragma unroll
  for (int i = 0; i < 32; i += 8)
    tile[ty + i][tx] = W[(size_t)(k0 + ty + i) * H_ + n0 + tx];
  __syncthreads();
#pragma unroll
  for (int i = 0; i < 32; i += 8) {
    int n = n0 + ty + i;
    Wt[(size_t)(mat * H_ + n) * E_ + k0 + tx] = f2bf(tile[tx][ty + i]);
  }
}

// ===== 8-phase 256x256x64 GEMM machinery =====
// LDS linear dest, pre-swizzled global source chunk; ds_read applies same XOR.
__device__ __forceinline__ void stage_half_A(
    const unsigned short* gA, int ld,
    unsigned short* ldsA, int mh, int w, int srow, int schunk) {
#pragma unroll
  for (int l = 0; l < 2; ++l) {
    const int row0 = l * 128 + mh * 64 + w * 8;
    __builtin_amdgcn_global_load_lds(
        (const __attribute__((address_space(1))) unsigned int*)(gA + (size_t)(row0 + srow) * ld + schunk * 8),
        (__attribute__((address_space(3))) unsigned int*)(ldsA + row0 * 64),
        16, 0, 0);
  }
}
__device__ __forceinline__ void stage_half_B(
    const unsigned short* gB, int ld,
    unsigned short* ldsB, int nh, int w, int srow, int schunk) {
#pragma unroll
  for (int l = 0; l < 2; ++l) {
    const int fi = (w * 2 + l) * 8;
    const int row0 = (fi >> 5) * 64 + nh * 32 + (fi & 31);
    __builtin_amdgcn_global_load_lds(
        (const __attribute__((address_space(1))) unsigned int*)(gB + (size_t)(row0 + srow) * ld + schunk * 8),
        (__attribute__((address_space(3))) unsigned int*)(ldsB + row0 * 64),
        16, 0, 0);
  }
}

// fragment reads (swizzled chunks c0/c1 precomputed per-thread)
#define READ_A(DST, MH, BUF)                                              \
  _Pragma("unroll") for (int fm = 0; fm < 4; ++fm) {                      \
    const int ra = wr * 128 + (MH) * 64 + fm * 16 + l15;                  \
    const unsigned short* ap = &As[(BUF) + ra * 64];                      \
    DST[fm][0] = *reinterpret_cast<const bf16x8*>(ap + c0 * 8);           \
    DST[fm][1] = *reinterpret_cast<const bf16x8*>(ap + c1 * 8);           \
  }
#define READ_B(DST, NH, BUF)                                              \
  _Pragma("unroll") for (int fn = 0; fn < 2; ++fn) {                      \
    const int rb = wc * 64 + (NH) * 32 + fn * 16 + l15;                   \
    const unsigned short* bp = &Bs[(BUF) + rb * 64];                      \
    DST[fn][0] = *reinterpret_cast<const bf16x8*>(bp + c0 * 8);           \
    DST[fn][1] = *reinterpret_cast<const bf16x8*>(bp + c1 * 8);           \
  }
#define MFMA_CLUSTER(AF, BF, MO, NO)                                      \
  __builtin_amdgcn_s_setprio(1);                                          \
  _Pragma("unroll") for (int fm = 0; fm < 4; ++fm)                        \
    _Pragma("unroll") for (int fn = 0; fn < 2; ++fn) {                    \
      acc[(MO) + fm][(NO) + fn] = __builtin_amdgcn_mfma_f32_16x16x32_bf16( \
          AF[fm][0], BF[fn][0], acc[(MO) + fm][(NO) + fn], 0, 0, 0);      \
      acc[(MO) + fm][(NO) + fn] = __builtin_amdgcn_mfma_f32_16x16x32_bf16( \
          AF[fm][1], BF[fn][1], acc[(MO) + fm][(NO) + fn], 0, 0, 0);      \
    }                                                                     \
  __builtin_amdgcn_s_setprio(0);
#define SYNC_RW()                                                         \
  __builtin_amdgcn_s_barrier();                                           \
  asm volatile("s_waitcnt lgkmcnt(0)" ::: "memory");                      \
  __builtin_amdgcn_sched_barrier(0);
#define ENDP() __builtin_amdgcn_s_barrier();

// ---------------- K1: fused QKV GEMM, 256x256 8-phase, Z-order reuse ----------------
__global__ __launch_bounds__(512, 2) void k_gemm_qkv8(
    const unsigned short* __restrict__ xb, const unsigned short* __restrict__ Wt,
    const float* __restrict__ bq, const float* __restrict__ bk,
    const float* __restrict__ bv,
    unsigned short* __restrict__ Qb, unsigned short* __restrict__ Kb,
    unsigned short* __restrict__ Vt) {
  __shared__ __align__(16) unsigned short As[2 * 256 * 64];  // 64 KiB
  __shared__ __align__(16) unsigned short Bs[2 * 256 * 64];  // 64 KiB
  int bid = blockIdx.x;                 // 384 = 8*48, bijective XCD swizzle
  bid = (bid & 7) * 48 + (bid >> 3);
  const int tm = bid / 12, tn = bid % 12;
  const int gm = tm * 256, gn = tn * 256;
  const int tid = threadIdx.x, w = tid >> 6, lane = tid & 63;
  const int wr = w >> 2, wc = w & 3;    // 2M x 4N waves; wave C = 128x64
  const int l15 = lane & 15, hi = lane >> 4;
  const int srow = lane >> 3, schunk = (lane & 7) ^ srow;
  const int c0 = hi ^ (lane & 7), c1 = c0 ^ 4;
  const unsigned short* gA = xb + (size_t)gm * E_;
  const unsigned short* gB = Wt + (size_t)gn * E_;

  f32x4 acc[8][4];
#pragma unroll
  for (int i = 0; i < 8; ++i)
#pragma unroll
    for (int j = 0; j < 4; ++j) acc[i][j] = (f32x4)0.0f;

  // prologue: tile0 fully + A0,B0 of tile1; wait for tile0 (4 instr in flight)
  stage_half_A(gA, E_, As, 0, w, srow, schunk);
  stage_half_A(gA, E_, As, 1, w, srow, schunk);
  stage_half_B(gB, E_, Bs, 0, w, srow, schunk);
  stage_half_B(gB, E_, Bs, 1, w, srow, schunk);
  stage_half_A(gA + 64, E_, As + 16384, 0, w, srow, schunk);
  stage_half_B(gB + 64, E_, Bs + 16384, 0, w, srow, schunk);
  asm volatile("s_waitcnt vmcnt(4)" ::: "memory");
  __builtin_amdgcn_s_barrier();

  for (int k = 0; k < 14; ++k) {
    const int ab = (k & 1) << 14, nb = ab ^ 16384;
    bf16x8 A0[4][2], A1[4][2], B0[2][2], B1[2][2];
    // PH1 (0,0): read A0+B0, stage A1(k+1)->nbuf
    READ_A(A0, 0, ab); READ_B(B0, 0, ab);
    stage_half_A(gA + (k + 1) * 64, E_, As + nb, 1, w, srow, schunk);
    SYNC_RW(); MFMA_CLUSTER(A0, B0, 0, 0); ENDP();
    // PH2 (0,1): read B1 (reuse A0), stage B1(k+1)->nbuf
    READ_B(B1, 1, ab);
    stage_half_B(gB + (k + 1) * 64, E_, Bs + nb, 1, w, srow, schunk);
    SYNC_RW(); MFMA_CLUSTER(A0, B1, 0, 2); ENDP();
    // PH3 (1,1): read A1 (reuse B1), stage A0(k+2)->abuf
    READ_A(A1, 1, ab);
    stage_half_A(gA + (k + 2) * 64, E_, As + ab, 0, w, srow, schunk);
    SYNC_RW(); MFMA_CLUSTER(A1, B1, 4, 2); ENDP();
    // PH4 (1,0): no reads (reuse A1,B0), stage B0(k+2)->abuf, K-tile vm wait
    stage_half_B(gB + (k + 2) * 64, E_, Bs + ab, 0, w, srow, schunk);
    __builtin_amdgcn_s_barrier();
    MFMA_CLUSTER(A1, B0, 4, 0);
    asm volatile("s_waitcnt vmcnt(4)" ::: "memory");
    __builtin_amdgcn_s_barrier();
  }
  {  // k = 14: stage last halves of tile 15 only; drain fully at end
    const int ab = 0, nb = 16384;
    bf16x8 A0[4][2], A1[4][2], B0[2][2], B1[2][2];
    READ_A(A0, 0, ab); READ_B(B0, 0, ab);
    stage_half_A(gA + 15 * 64, E_, As + nb, 1, w, srow, schunk);
    SYNC_RW(); MFMA_CLUSTER(A0, B0, 0, 0); ENDP();
    READ_B(B1, 1, ab);
    stage_half_B(gB + 15 * 64, E_, Bs + nb, 1, w, srow, schunk);
    SYNC_RW(); MFMA_CLUSTER(A0, B1, 0, 2); ENDP();
    READ_A(A1, 1, ab);
    SYNC_RW(); MFMA_CLUSTER(A1, B1, 4, 2); ENDP();
    __builtin_amdgcn_s_barrier();
    MFMA_CLUSTER(A1, B0, 4, 0);
    asm volatile("s_waitcnt vmcnt(0)" ::: "memory");
    __builtin_amdgcn_s_barrier();
  }
  {  // k = 15: compute only
    const int ab = 16384;
    bf16x8 A0[4][2], A1[4][2], B0[2][2], B1[2][2];
    READ_A(A0, 0, ab); READ_B(B0, 0, ab);
    SYNC_RW(); MFMA_CLUSTER(A0, B0, 0, 0); ENDP();
    READ_B(B1, 1, ab);
    SYNC_RW(); MFMA_CLUSTER(A0, B1, 0, 2); ENDP();
    READ_A(A1, 1, ab);
    SYNC_RW(); MFMA_CLUSTER(A1, B1, 4, 2); ENDP();
    __builtin_amdgcn_s_barrier();
    MFMA_CLUSTER(A1, B0, 4, 0);
  }

  // epilogue: bias, bf16, scatter Q/K row-major or V transposed
  const int matid = gn >> 10;
  const float* bias = (matid == 0) ? bq : (matid == 1) ? bk : bv;
#pragma unroll
  for (int mf = 0; mf < 8; ++mf) {
#pragma unroll
    for (int nf = 0; nf < 4; ++nf) {
      const int row0 = gm + wr * 128 + mf * 16 + hi * 4;
      const int col = gn + wc * 64 + nf * 16 + l15;
      const int h = col & 1023;
      const float bb = bias[h];
      if (matid < 2) {
        unsigned short* dst = matid ? Kb : Qb;
#pragma unroll
        for (int r = 0; r < 4; ++r)
          dst[(size_t)(row0 + r) * H_ + h] = f2bf(acc[mf][nf][r] + bb);
      } else {
        const int bat = row0 >> 11, s0 = row0 & 2047;
        us4 pk;
#pragma unroll
        for (int r = 0; r < 4; ++r) pk[r] = f2bf(acc[mf][nf][r] + bb);
        *reinterpret_cast<us4*>(&Vt[(size_t)bat * H_ * S_ + (size_t)h * S_ + s0]) = pk;
      }
    }
  }
}

// ------- K2: scores GEMM (m97 128x128), lower-tri tiles only, packed out -------
__global__ __launch_bounds__(256, 2) void k_gemm_scores(
    const unsigned short* __restrict__ Qb, const unsigned short* __restrict__ Kb,
    unsigned short* __restrict__ Pt) {
  __shared__ unsigned short As[128 * 64];
  __shared__ unsigned short Bs[128 * 64];
  int bid = blockIdx.x;                  // 544 = 8*68, bijective XCD swizzle
  bid = (bid & 7) * 68 + (bid >> 3);
  const int batch = bid / NTRI_;
  const int t = bid % NTRI_;
  int tm = 0;
  while ((tm + 1) * (tm + 2) / 2 <= t) ++tm;
  const int tn = t - tm * (tm + 1) / 2;
  const int gm = tm * 128, gn = tn * 128;
  const int tid = threadIdx.x, w = tid >> 6, lane = tid & 63;
  const int wr = w >> 1, wc = w & 1;
  const int srow = lane >> 3;
  const int schunk = (lane & 7) ^ srow;
  const unsigned short* Abase = Qb + (size_t)batch * S_ * H_;
  const unsigned short* Bbase = Kb + (size_t)batch * S_ * H_;

  f32x4 acc[4][4];
#pragma unroll
  for (int i = 0; i < 4; ++i)
#pragma unroll
    for (int j = 0; j < 4; ++j) acc[i][j] = (f32x4)0.0f;

  for (int kt = 0; kt < 16; ++kt) {
    const int k0 = kt * 64;
#pragma unroll
    for (int i = 0; i < 4; ++i) {
      const int row = w * 32 + i * 8 + srow;
      __builtin_amdgcn_global_load_lds(
          (const __attribute__((address_space(1))) unsigned int*)(Abase + (size_t)(gm + row) * H_ + k0 + schunk * 8),
          (__attribute__((address_space(3))) unsigned int*)(As + (w * 32 + i * 8) * 64),
          16, 0, 0);
      __builtin_amdgcn_global_load_lds(
          (const __attribute__((address_space(1))) unsigned int*)(Bbase + (size_t)(gn + row) * H_ + k0 + schunk * 8),
          (__attribute__((address_space(3))) unsigned int*)(Bs + (w * 32 + i * 8) * 64),
          16, 0, 0);
    }
    __syncthreads();
#pragma unroll
    for (int ks = 0; ks < 2; ++ks) {
      bf16x8 af[4], bfrag[4];
#pragma unroll
      for (int mt = 0; mt < 4; ++mt) {
        const int r16 = wr * 64 + mt * 16 + (lane & 15);
        const int ch = (ks * 4 + (lane >> 4)) ^ (r16 & 7);
        af[mt] = *reinterpret_cast<const bf16x8*>(&As[r16 * 64 + ch * 8]);
      }
#pragma unroll
      for (int nt = 0; nt < 4; ++nt) {
        const int c16 = wc * 64 + nt * 16 + (lane & 15);
        const int ch = (ks * 4 + (lane >> 4)) ^ (c16 & 7);
        bfrag[nt] = *reinterpret_cast<const bf16x8*>(&Bs[c16 * 64 + ch * 8]);
      }
#pragma unroll
      for (int mt = 0; mt < 4; ++mt)
#pragma unroll
        for (int nt = 0; nt < 4; ++nt)
          acc[mt][nt] = __builtin_amdgcn_mfma_f32_16x16x32_bf16(
              af[mt], bfrag[nt], acc[mt][nt], 0, 0, 0);
    }
    __syncthreads();
  }

  const size_t tbase = ((size_t)batch * NTRI_ + (tm * (tm + 1)) / 2 + tn) * 16384;
#pragma unroll
  for (int mt = 0; mt < 4; ++mt) {
#pragma unroll
    for (int nt = 0; nt < 4; ++nt) {
      const int row0 = wr * 64 + mt * 16 + (lane >> 4) * 4;
      const int col = wc * 64 + nt * 16 + (lane & 15);
#pragma unroll
      for (int r = 0; r < 4; ++r)
        Pt[tbase + (size_t)(row0 + r) * 128 + col] = f2bf(acc[mt][nt][r] * 0.03125f);
    }
  }
}

// ------- K3: in-place causal row softmax over packed tri tiles -------
__global__ __launch_bounds__(256) void k_softmax(unsigned short* __restrict__ Pt) {
  const int tid = threadIdx.x, lane = tid & 63;
  const int gr = blockIdx.x * 4 + (tid >> 6);
  const int batch = gr >> 11, q = gr & 2047;
  const int tm = q >> 7, r = q & 127;
  const int W = (tm + 1) << 7;
  const size_t rowb = ((size_t)batch * NTRI_ + (tm * (tm + 1)) / 2) * 16384 + (size_t)r * 128;

  float s[32];
  float mx = -1e30f;
#pragma unroll
  for (int it = 0; it < 4; ++it) {
    const int c = it * 512 + lane * 8;
    if (c < W) {
      const int tn = c >> 7;
      const bf16x8 v = *reinterpret_cast<const bf16x8*>(&Pt[rowb + (size_t)tn * 16384 + (c & 127)]);
#pragma unroll
      for (int j = 0; j < 8; ++j) {
        float f = bf2f((unsigned short)v[j]);
        if (c + j > q) f = -1e30f;
        s[it * 8 + j] = f;
        mx = fmaxf(mx, f);
      }
    } else {
#pragma unroll
      for (int j = 0; j < 8; ++j) s[it * 8 + j] = -1e30f;
    }
  }
#pragma unroll
  for (int off = 32; off; off >>= 1) mx = fmaxf(mx, __shfl_xor(mx, off));
  float sum = 0.f;
#pragma unroll
  for (int it = 0; it < 4; ++it)
#pragma unroll
    for (int j = 0; j < 8; ++j) {
      const float p = __expf(s[it * 8 + j] - mx);
      s[it * 8 + j] = p;
      sum += p;
    }
#pragma unroll
  for (int off = 32; off; off >>= 1) sum += __shfl_xor(sum, off);
  const float inv = 1.0f / sum;
#pragma unroll
  for (int it = 0; it < 4; ++it) {
    const int c = it * 512 + lane * 8;
    if (c < W) {
      const int tn = c >> 7;
      bf16x8 o;
#pragma unroll
      for (int j = 0; j < 8; ++j) o[j] = (short)f2bf(s[it * 8 + j] * inv);
      *reinterpret_cast<bf16x8*>(&Pt[rowb + (size_t)tn * 16384 + (c & 127)]) = o;
    }
  }
}

// ------- K4: O = P.V GEMM, variable-K, heavy/light CU pairing -------
__global__ __launch_bounds__(256, 2) void k_gemm_pv(
    const unsigned short* __restrict__ Pt, const unsigned short* __restrict__ Vt,
    float* __restrict__ out) {
  __shared__ unsigned short As[128 * 64];
  __shared__ unsigned short Bs[128 * 64];
  const int b0 = blockIdx.x;
  const int rk = (b0 < 256) ? b0 : 767 - b0;
  const int tm = 15 - (rk >> 5);
  const int batch = (rk >> 3) & 3;
  const int tn = rk & 7;
  const int gm = tm * 128, gn = tn * 128;
  const int tid = threadIdx.x, w = tid >> 6, lane = tid & 63;
  const int wr = w >> 1, wc = w & 1;
  const int srow = lane >> 3;
  const int schunk = (lane & 7) ^ srow;
  const size_t trow = ((size_t)batch * NTRI_ + (tm * (tm + 1)) / 2) * 16384;
  const unsigned short* Bbase = Vt + (size_t)batch * H_ * S_;
  const int nk = (tm + 1) * 2;

  f32x4 acc[4][4];
#pragma unroll
  for (int i = 0; i < 4; ++i)
#pragma unroll
    for (int j = 0; j < 4; ++j) acc[i][j] = (f32x4)0.0f;

  for (int kt = 0; kt < nk; ++kt) {
    const int ktn = kt >> 1, cin = (kt & 1) * 64;
#pragma unroll
    for (int i = 0; i < 4; ++i) {
      const int row = w * 32 + i * 8 + srow;
      __builtin_amdgcn_global_load_lds(
          (const __attribute__((address_space(1))) unsigned int*)(Pt + trow + (size_t)ktn * 16384 + (size_t)row * 128 + cin + schunk * 8),
          (__attribute__((address_space(3))) unsigned int*)(As + (w * 32 + i * 8) * 64),
          16, 0, 0);
      __builtin_amdgcn_global_load_lds(
          (const __attribute__((address_space(1))) unsigned int*)(Bbase + (size_t)(gn + row) * S_ + kt * 64 + schunk * 8),
          (__attribute__((address_space(3))) unsigned int*)(Bs + (w * 32 + i * 8) * 64),
          16, 0, 0);
    }
    __syncthreads();
#pragma unroll
    for (int ks = 0; ks < 2; ++ks) {
      bf16x8 af[4], bfrag[4];
#pragma unroll
      for (int mt = 0; mt < 4; ++mt) {
        const int r16 = wr * 64 + mt * 16 + (lane & 15);
        const int ch = (ks * 4 + (lane >> 4)) ^ (r16 & 7);
        af[mt] = *reinterpret_cast<const bf16x8*>(&As[r16 * 64 + ch * 8]);
      }
#pragma unroll
      for (int nt = 0; nt < 4; ++nt) {
        const int c16 = wc * 64 + nt * 16 + (lane & 15);
        const int ch = (ks * 4 + (lane >> 4)) ^ (c16 & 7);
        bfrag[nt] = *reinterpret_cast<const bf16x8*>(&Bs[c16 * 64 + ch * 8]);
      }
#pragma unroll
      for (int mt = 0; mt < 4; ++mt)
#pragma unroll
        for (int nt = 0; nt < 4; ++nt)
          acc[mt][nt] = __builtin_amdgcn_mfma_f32_16x16x32_bf16(
              af[mt], bfrag[nt], acc[mt][nt], 0, 0, 0);
    }
    __syncthreads();
  }

#pragma unroll
  for (int mt = 0; mt < 4; ++mt) {
#pragma unroll
    for (int nt = 0; nt < 4; ++nt) {
      const int row0 = gm + wr * 64 + mt * 16 + (lane >> 4) * 4;
      const int col = gn + wc * 64 + nt * 16 + (lane & 15);
#pragma unroll
      for (int r = 0; r < 4; ++r)
        out[(size_t)batch * S_ * H_ + (size_t)(row0 + r) * H_ + col] = acc[mt][nt][r];
    }
  }
}

extern "C" void kernel_launch(void* const* d_in, const int* in_sizes, int n_in,
                              void* d_out, int out_size, void* d_ws, size_t ws_size,
                              hipStream_t stream) {
  const float* x  = (const float*)d_in[0];
  const float* Wq = (const float*)d_in[1];
  const float* bq = (const float*)d_in[2];
  const float* Wk = (const float*)d_in[3];
  const float* bk = (const float*)d_in[4];
  const float* Wv = (const float*)d_in[5];
  const float* bv = (const float*)d_in[6];
  float* out = (float*)d_out;

  unsigned short* Qb = (unsigned short*)d_ws;
  unsigned short* Kb = Qb + (size_t)M_ * H_;
  unsigned short* Vt = Kb + (size_t)M_ * H_;
  unsigned short* Xr = Vt + (size_t)M_ * H_;
  unsigned short* xb = Xr;
  unsigned short* Wt = Xr + (size_t)M_ * E_;
  unsigned short* Pt = Xr;

  hipLaunchKernelGGL(k_convert_x, dim3(M_ * E_ / 1024), dim3(256), 0, stream, x, xb);
  hipLaunchKernelGGL(k_transpose_w, dim3(32, 32, 3), dim3(32, 8), 0, stream, Wq, Wk, Wv, Wt);
  hipLaunchKernelGGL(k_gemm_qkv8, dim3(384), dim3(512), 0, stream,
                     xb, Wt, bq, bk, bv, Qb, Kb, Vt);
  hipLaunchKernelGGL(k_gemm_scores, dim3(544), dim3(256), 0, stream, Qb, Kb, Pt);
  hipLaunchKernelGGL(k_softmax, dim3(2048), dim3(256), 0, stream, Pt);
  hipLaunchKernelGGL(k_gemm_pv, dim3(512), dim3(256), 0, stream, Pt, Vt, out);
}

// Round 5
// 154.501 us; speedup vs baseline: 1.1103x; 1.0213x over previous
//
#include <hip/hip_runtime.h>
#include <hip/hip_bf16.h>

typedef __attribute__((ext_vector_type(8))) short bf16x8;
typedef __attribute__((ext_vector_type(4))) float f32x4;
typedef __attribute__((ext_vector_type(4))) unsigned short us4;

#define B_ 4
#define S_ 2048
#define E_ 1024
#define H_ 1024
#define M_ (B_ * S_)   // 8192 tokens
#define N3_ (3 * H_)   // 3072 fused QKV columns
#define NTRI_ 136      // lower-tri 128-tiles per batch (16*17/2)

__device__ __forceinline__ unsigned short f2bf(float f) {
  union { float f; unsigned u; } v; v.f = f;
  unsigned r = v.u + 0x7fffu + ((v.u >> 16) & 1u);  // RNE
  return (unsigned short)(r >> 16);
}
__device__ __forceinline__ float bf2f(unsigned short u) {
  union { unsigned u; float f; } v; v.u = ((unsigned)u) << 16; return v.f;
}

// ---------------- K0a: x fp32 -> bf16 (vectorized) ----------------
__global__ __launch_bounds__(256) void k_convert_x(const float* __restrict__ x,
                                                   unsigned short* __restrict__ xb) {
  int i = blockIdx.x * 256 + threadIdx.x;
  const float4 v = reinterpret_cast<const float4*>(x)[i];
  us4 o;
  o[0] = f2bf(v.x); o[1] = f2bf(v.y); o[2] = f2bf(v.z); o[3] = f2bf(v.w);
  reinterpret_cast<us4*>(xb)[i] = o;
}

// ------- K0b: W[E][H] fp32 -> Wt[3H][E] bf16 (transposed, LDS tile) -------
__global__ __launch_bounds__(256) void k_transpose_w(const float* __restrict__ Wq,
                                                     const float* __restrict__ Wk,
                                                     const float* __restrict__ Wv,
                                                     unsigned short* __restrict__ Wt) {
  __shared__ float tile[32][33];
  const int mat = blockIdx.z;
  const float* W = (mat == 0) ? Wq : (mat == 1) ? Wk : Wv;
  const int n0 = blockIdx.x * 32, k0 = blockIdx.y * 32;
  const int tx = threadIdx.x, ty = threadIdx.y;
#pragma unroll
  for (int i = 0; i < 32; i += 8)
    tile[ty + i][tx] = W[(size_t)(k0 + ty + i) * H_ + n0 + tx];
  __syncthreads();
#pragma unroll
  for (int i = 0; i < 32; i += 8) {
    int n = n0 + ty + i;
    Wt[(size_t)(mat * H_ + n) * E_ + k0 + tx] = f2bf(tile[tx][ty + i]);
  }
}

// ---------------- K1: fused QKV GEMM, 128x256 tile, m97 2-phase ----------------
// 768 blocks = exactly 3 per CU. acc[4][8] per thread (wave C = 64x128).
__global__ __launch_bounds__(256, 2) void k_gemm_qkv(
    const unsigned short* __restrict__ xb, const unsigned short* __restrict__ Wt,
    const float* __restrict__ bq, const float* __restrict__ bk,
    const float* __restrict__ bv,
    unsigned short* __restrict__ Qb, unsigned short* __restrict__ Kb,
    unsigned short* __restrict__ Vt) {
  __shared__ unsigned short As[128 * 64];  // 16 KiB
  __shared__ unsigned short Bs[256 * 64];  // 32 KiB
  int bid = blockIdx.x;                    // 768 = 8*96, bijective XCD swizzle
  bid = (bid & 7) * 96 + (bid >> 3);
  const int tm = bid / 12, tn = bid % 12;
  const int gm = tm * 128, gn = tn * 256;
  const int tid = threadIdx.x, w = tid >> 6, lane = tid & 63;
  const int wr = w >> 1, wc = w & 1;       // wave C = 64 rows x 128 cols
  const int l15 = lane & 15, hi = lane >> 4;
  const int srow = lane >> 3;
  const int schunk = (lane & 7) ^ srow;    // pre-swizzled source 16B chunk
  const unsigned short* gA = xb + (size_t)gm * E_;
  const unsigned short* gB = Wt + (size_t)gn * E_;

  f32x4 acc[4][8];
#pragma unroll
  for (int i = 0; i < 4; ++i)
#pragma unroll
    for (int j = 0; j < 8; ++j) acc[i][j] = (f32x4)0.0f;

  for (int kt = 0; kt < 16; ++kt) {
    const int k0 = kt * 64;
#pragma unroll
    for (int i = 0; i < 4; ++i) {          // A: 128 rows
      const int row = w * 32 + i * 8 + srow;
      __builtin_amdgcn_global_load_lds(
          (const __attribute__((address_space(1))) unsigned int*)(gA + (size_t)row * E_ + k0 + schunk * 8),
          (__attribute__((address_space(3))) unsigned int*)(As + (w * 32 + i * 8) * 64),
          16, 0, 0);
    }
#pragma unroll
    for (int i = 0; i < 8; ++i) {          // B: 256 rows
      const int row = w * 64 + i * 8 + srow;
      __builtin_amdgcn_global_load_lds(
          (const __attribute__((address_space(1))) unsigned int*)(gB + (size_t)row * E_ + k0 + schunk * 8),
          (__attribute__((address_space(3))) unsigned int*)(Bs + (w * 64 + i * 8) * 64),
          16, 0, 0);
    }
    __syncthreads();
#pragma unroll
    for (int ks = 0; ks < 2; ++ks) {
      bf16x8 af[4], bfrag[8];
#pragma unroll
      for (int mt = 0; mt < 4; ++mt) {
        const int ra = wr * 64 + mt * 16 + l15;
        const int ch = (ks * 4 + hi) ^ (ra & 7);
        af[mt] = *reinterpret_cast<const bf16x8*>(&As[ra * 64 + ch * 8]);
      }
#pragma unroll
      for (int nt = 0; nt < 8; ++nt) {
        const int rb = wc * 128 + nt * 16 + l15;
        const int ch = (ks * 4 + hi) ^ (rb & 7);
        bfrag[nt] = *reinterpret_cast<const bf16x8*>(&Bs[rb * 64 + ch * 8]);
      }
#pragma unroll
      for (int mt = 0; mt < 4; ++mt)
#pragma unroll
        for (int nt = 0; nt < 8; ++nt)
          acc[mt][nt] = __builtin_amdgcn_mfma_f32_16x16x32_bf16(
              af[mt], bfrag[nt], acc[mt][nt], 0, 0, 0);
    }
    __syncthreads();
  }

  // epilogue: bias add, bf16 convert, scatter Q/K row-major or V transposed
  const int matid = gn >> 10;  // uniform per block (256 | 1024)
  const float* bias = (matid == 0) ? bq : (matid == 1) ? bk : bv;
#pragma unroll
  for (int mt = 0; mt < 4; ++mt) {
#pragma unroll
    for (int nt = 0; nt < 8; ++nt) {
      const int row0 = gm + wr * 64 + mt * 16 + hi * 4;
      const int col = gn + wc * 128 + nt * 16 + l15;
      const int h = col & 1023;
      const float bb = bias[h];
      if (matid < 2) {
        unsigned short* dst = matid ? Kb : Qb;
#pragma unroll
        for (int r = 0; r < 4; ++r)
          dst[(size_t)(row0 + r) * H_ + h] = f2bf(acc[mt][nt][r] + bb);
      } else {
        const int bat = row0 >> 11, s0 = row0 & 2047;
        us4 pk;
#pragma unroll
        for (int r = 0; r < 4; ++r) pk[r] = f2bf(acc[mt][nt][r] + bb);
        *reinterpret_cast<us4*>(&Vt[(size_t)bat * H_ * S_ + (size_t)h * S_ + s0]) = pk;
      }
    }
  }
}

// ------- K2: scores GEMM (m97 128x128), lower-tri tiles only, packed out -------
__global__ __launch_bounds__(256, 2) void k_gemm_scores(
    const unsigned short* __restrict__ Qb, const unsigned short* __restrict__ Kb,
    unsigned short* __restrict__ Pt) {
  __shared__ unsigned short As[128 * 64];
  __shared__ unsigned short Bs[128 * 64];
  int bid = blockIdx.x;                  // 544 = 8*68, bijective XCD swizzle
  bid = (bid & 7) * 68 + (bid >> 3);
  const int batch = bid / NTRI_;
  const int t = bid % NTRI_;
  int tm = 0;
  while ((tm + 1) * (tm + 2) / 2 <= t) ++tm;
  const int tn = t - tm * (tm + 1) / 2;
  const int gm = tm * 128, gn = tn * 128;
  const int tid = threadIdx.x, w = tid >> 6, lane = tid & 63;
  const int wr = w >> 1, wc = w & 1;
  const int srow = lane >> 3;
  const int schunk = (lane & 7) ^ srow;
  const unsigned short* Abase = Qb + (size_t)batch * S_ * H_;
  const unsigned short* Bbase = Kb + (size_t)batch * S_ * H_;

  f32x4 acc[4][4];
#pragma unroll
  for (int i = 0; i < 4; ++i)
#pragma unroll
    for (int j = 0; j < 4; ++j) acc[i][j] = (f32x4)0.0f;

  for (int kt = 0; kt < 16; ++kt) {
    const int k0 = kt * 64;
#pragma unroll
    for (int i = 0; i < 4; ++i) {
      const int row = w * 32 + i * 8 + srow;
      __builtin_amdgcn_global_load_lds(
          (const __attribute__((address_space(1))) unsigned int*)(Abase + (size_t)(gm + row) * H_ + k0 + schunk * 8),
          (__attribute__((address_space(3))) unsigned int*)(As + (w * 32 + i * 8) * 64),
          16, 0, 0);
      __builtin_amdgcn_global_load_lds(
          (const __attribute__((address_space(1))) unsigned int*)(Bbase + (size_t)(gn + row) * H_ + k0 + schunk * 8),
          (__attribute__((address_space(3))) unsigned int*)(Bs + (w * 32 + i * 8) * 64),
          16, 0, 0);
    }
    __syncthreads();
#pragma unroll
    for (int ks = 0; ks < 2; ++ks) {
      bf16x8 af[4], bfrag[4];
#pragma unroll
      for (int mt = 0; mt < 4; ++mt) {
        const int r16 = wr * 64 + mt * 16 + (lane & 15);
        const int ch = (ks * 4 + (lane >> 4)) ^ (r16 & 7);
        af[mt] = *reinterpret_cast<const bf16x8*>(&As[r16 * 64 + ch * 8]);
      }
#pragma unroll
      for (int nt = 0; nt < 4; ++nt) {
        const int c16 = wc * 64 + nt * 16 + (lane & 15);
        const int ch = (ks * 4 + (lane >> 4)) ^ (c16 & 7);
        bfrag[nt] = *reinterpret_cast<const bf16x8*>(&Bs[c16 * 64 + ch * 8]);
      }
#pragma unroll
      for (int mt = 0; mt < 4; ++mt)
#pragma unroll
        for (int nt = 0; nt < 4; ++nt)
          acc[mt][nt] = __builtin_amdgcn_mfma_f32_16x16x32_bf16(
              af[mt], bfrag[nt], acc[mt][nt], 0, 0, 0);
    }
    __syncthreads();
  }

  const size_t tbase = ((size_t)batch * NTRI_ + (tm * (tm + 1)) / 2 + tn) * 16384;
#pragma unroll
  for (int mt = 0; mt < 4; ++mt) {
#pragma unroll
    for (int nt = 0; nt < 4; ++nt) {
      const int row0 = wr * 64 + mt * 16 + (lane >> 4) * 4;
      const int col = wc * 64 + nt * 16 + (lane & 15);
#pragma unroll
      for (int r = 0; r < 4; ++r)
        Pt[tbase + (size_t)(row0 + r) * 128 + col] = f2bf(acc[mt][nt][r] * 0.03125f);
    }
  }
}

// ------- K3: in-place causal row softmax over packed tri tiles -------
__global__ __launch_bounds__(256) void k_softmax(unsigned short* __restrict__ Pt) {
  const int tid = threadIdx.x, lane = tid & 63;
  const int gr = blockIdx.x * 4 + (tid >> 6);
  const int batch = gr >> 11, q = gr & 2047;
  const int tm = q >> 7, r = q & 127;
  const int W = (tm + 1) << 7;
  const size_t rowb = ((size_t)batch * NTRI_ + (tm * (tm + 1)) / 2) * 16384 + (size_t)r * 128;

  float s[32];
  float mx = -1e30f;
#pragma unroll
  for (int it = 0; it < 4; ++it) {
    const int c = it * 512 + lane * 8;
    if (c < W) {
      const int tn = c >> 7;
      const bf16x8 v = *reinterpret_cast<const bf16x8*>(&Pt[rowb + (size_t)tn * 16384 + (c & 127)]);
#pragma unroll
      for (int j = 0; j < 8; ++j) {
        float f = bf2f((unsigned short)v[j]);
        if (c + j > q) f = -1e30f;
        s[it * 8 + j] = f;
        mx = fmaxf(mx, f);
      }
    } else {
#pragma unroll
      for (int j = 0; j < 8; ++j) s[it * 8 + j] = -1e30f;
    }
  }
#pragma unroll
  for (int off = 32; off; off >>= 1) mx = fmaxf(mx, __shfl_xor(mx, off));
  float sum = 0.f;
#pragma unroll
  for (int it = 0; it < 4; ++it)
#pragma unroll
    for (int j = 0; j < 8; ++j) {
      const float p = __expf(s[it * 8 + j] - mx);
      s[it * 8 + j] = p;
      sum += p;
    }
#pragma unroll
  for (int off = 32; off; off >>= 1) sum += __shfl_xor(sum, off);
  const float inv = 1.0f / sum;
#pragma unroll
  for (int it = 0; it < 4; ++it) {
    const int c = it * 512 + lane * 8;
    if (c < W) {
      const int tn = c >> 7;
      bf16x8 o;
#pragma unroll
      for (int j = 0; j < 8; ++j) o[j] = (short)f2bf(s[it * 8 + j] * inv);
      *reinterpret_cast<bf16x8*>(&Pt[rowb + (size_t)tn * 16384 + (c & 127)]) = o;
    }
  }
}

// ------- K4: O = P.V GEMM, variable-K, heavy/light CU pairing -------
__global__ __launch_bounds__(256, 2) void k_gemm_pv(
    const unsigned short* __restrict__ Pt, const unsigned short* __restrict__ Vt,
    float* __restrict__ out) {
  __shared__ unsigned short As[128 * 64];
  __shared__ unsigned short Bs[128 * 64];
  const int b0 = blockIdx.x;
  const int rk = (b0 < 256) ? b0 : 767 - b0;
  const int tm = 15 - (rk >> 5);
  const int batch = (rk >> 3) & 3;
  const int tn = rk & 7;
  const int gm = tm * 128, gn = tn * 128;
  const int tid = threadIdx.x, w = tid >> 6, lane = tid & 63;
  const int wr = w >> 1, wc = w & 1;
  const int srow = lane >> 3;
  const int schunk = (lane & 7) ^ srow;
  const size_t trow = ((size_t)batch * NTRI_ + (tm * (tm + 1)) / 2) * 16384;
  const unsigned short* Bbase = Vt + (size_t)batch * H_ * S_;
  const int nk = (tm + 1) * 2;

  f32x4 acc[4][4];
#pragma unroll
  for (int i = 0; i < 4; ++i)
#pragma unroll
    for (int j = 0; j < 4; ++j) acc[i][j] = (f32x4)0.0f;

  for (int kt = 0; kt < nk; ++kt) {
    const int ktn = kt >> 1, cin = (kt & 1) * 64;
#pragma unroll
    for (int i = 0; i < 4; ++i) {
      const int row = w * 32 + i * 8 + srow;
      __builtin_amdgcn_global_load_lds(
          (const __attribute__((address_space(1))) unsigned int*)(Pt + trow + (size_t)ktn * 16384 + (size_t)row * 128 + cin + schunk * 8),
          (__attribute__((address_space(3))) unsigned int*)(As + (w * 32 + i * 8) * 64),
          16, 0, 0);
      __builtin_amdgcn_global_load_lds(
          (const __attribute__((address_space(1))) unsigned int*)(Bbase + (size_t)(gn + row) * S_ + kt * 64 + schunk * 8),
          (__attribute__((address_space(3))) unsigned int*)(Bs + (w * 32 + i * 8) * 64),
          16, 0, 0);
    }
    __syncthreads();
#pragma unroll
    for (int ks = 0; ks < 2; ++ks) {
      bf16x8 af[4], bfrag[4];
#pragma unroll
      for (int mt = 0; mt < 4; ++mt) {
        const int r16 = wr * 64 + mt * 16 + (lane & 15);
        const int ch = (ks * 4 + (lane >> 4)) ^ (r16 & 7);
        af[mt] = *reinterpret_cast<const bf16x8*>(&As[r16 * 64 + ch * 8]);
      }
#pragma unroll
      for (int nt = 0; nt < 4; ++nt) {
        const int c16 = wc * 64 + nt * 16 + (lane & 15);
        const int ch = (ks * 4 + (lane >> 4)) ^ (c16 & 7);
        bfrag[nt] = *reinterpret_cast<const bf16x8*>(&Bs[c16 * 64 + ch * 8]);
      }
#pragma unroll
      for (int mt = 0; mt < 4; ++mt)
#pragma unroll
        for (int nt = 0; nt < 4; ++nt)
          acc[mt][nt] = __builtin_amdgcn_mfma_f32_16x16x32_bf16(
              af[mt], bfrag[nt], acc[mt][nt], 0, 0, 0);
    }
    __syncthreads();
  }

#pragma unroll
  for (int mt = 0; mt < 4; ++mt) {
#pragma unroll
    for (int nt = 0; nt < 4; ++nt) {
      const int row0 = gm + wr * 64 + mt * 16 + (lane >> 4) * 4;
      const int col = gn + wc * 64 + nt * 16 + (lane & 15);
#pragma unroll
      for (int r = 0; r < 4; ++r)
        out[(size_t)batch * S_ * H_ + (size_t)(row0 + r) * H_ + col] = acc[mt][nt][r];
    }
  }
}

extern "C" void kernel_launch(void* const* d_in, const int* in_sizes, int n_in,
                              void* d_out, int out_size, void* d_ws, size_t ws_size,
                              hipStream_t stream) {
  const float* x  = (const float*)d_in[0];
  const float* Wq = (const float*)d_in[1];
  const float* bq = (const float*)d_in[2];
  const float* Wk = (const float*)d_in[3];
  const float* bk = (const float*)d_in[4];
  const float* Wv = (const float*)d_in[5];
  const float* bv = (const float*)d_in[6];
  float* out = (float*)d_out;

  unsigned short* Qb = (unsigned short*)d_ws;
  unsigned short* Kb = Qb + (size_t)M_ * H_;
  unsigned short* Vt = Kb + (size_t)M_ * H_;
  unsigned short* Xr = Vt + (size_t)M_ * H_;
  unsigned short* xb = Xr;
  unsigned short* Wt = Xr + (size_t)M_ * E_;
  unsigned short* Pt = Xr;

  hipLaunchKernelGGL(k_convert_x, dim3(M_ * E_ / 1024), dim3(256), 0, stream, x, xb);
  hipLaunchKernelGGL(k_transpose_w, dim3(32, 32, 3), dim3(32, 8), 0, stream, Wq, Wk, Wv, Wt);
  hipLaunchKernelGGL(k_gemm_qkv, dim3(768), dim3(256), 0, stream,
                     xb, Wt, bq, bk, bv, Qb, Kb, Vt);
  hipLaunchKernelGGL(k_gemm_scores, dim3(544), dim3(256), 0, stream, Qb, Kb, Pt);
  hipLaunchKernelGGL(k_softmax, dim3(2048), dim3(256), 0, stream, Pt);
  hipLaunchKernelGGL(k_gemm_pv, dim3(512), dim3(256), 0, stream, Pt, Vt, out);
}